// Round 2
// baseline (64.235 us; speedup 1.0000x reference)
//
#include <hip/hip_runtime.h>
#include <hip/hip_bf16.h>

// Closed form of the 16-qubit circuit:
//   ev[b,i] = prod_{k in S_i} cos(h[b,k]),  S_i = {k<=i : (i-k) mod 4 in {0,1}}
// where h = x@w_in^T + b_in. The RZ phases (q_weights) provably cancel in
// |amp|^2 (diagonal unitaries + basis permutations only), and the CNOT-chain
// permutation applied 3x is the GF(2) map L^3 with (L^3)_{ik}=1 iff
// (i-k) mod 4 in {0,1}. Parity expectation of independent RY qubits is the
// product of cos(theta_k). out = ev@w_out^T + b_out.
// All reference dtypes are float32.

#define NQ 16
#define D  128

__global__ __launch_bounds__(128) void qlayer_kernel(
    const float* __restrict__ x,      // [B, 128]
    const float* __restrict__ w_in,   // [16, 128]
    const float* __restrict__ b_in,   // [16]
    const float* __restrict__ w_out,  // [128, 16]
    const float* __restrict__ b_out,  // [128]
    float* __restrict__ out)          // [B, 128]
{
    __shared__ float s_x[D];
    __shared__ float s_part[D];
    __shared__ float s_cos[NQ];
    __shared__ float s_ev[NQ];

    const int b = blockIdx.x;
    const int t = threadIdx.x;  // 0..127

    // stage x row into LDS
    s_x[t] = x[b * D + t];
    __syncthreads();

    // h[i] = dot(x_row, w_in[i,:]) + b_in[i]; 8 threads per i, 16 elems each
    const int i = t >> 3;   // 0..15
    const int j = t & 7;    // 0..7
    const int d0 = j * 16;
    float p = 0.f;
#pragma unroll
    for (int d = 0; d < 16; ++d)
        p += s_x[d0 + d] * w_in[i * D + d0 + d];
    s_part[t] = p;
    __syncthreads();

    if (t < NQ) {
        float h = b_in[t];
#pragma unroll
        for (int jj = 0; jj < 8; ++jj) h += s_part[t * 8 + jj];
        s_cos[t] = cosf(h);
    }
    __syncthreads();

    if (t < NQ) {
        float pr = 1.f;
#pragma unroll
        for (int k = 0; k < NQ; ++k) {
            if (k <= t && (((t - k) & 3) < 2)) pr *= s_cos[k];
        }
        s_ev[t] = pr;
    }
    __syncthreads();

    // out[b, t] = dot(ev, w_out[t, :]) + b_out[t]
    float o = b_out[t];
#pragma unroll
    for (int q = 0; q < NQ; ++q)
        o += s_ev[q] * w_out[t * NQ + q];
    out[b * D + t] = o;
}

extern "C" void kernel_launch(void* const* d_in, const int* in_sizes, int n_in,
                              void* d_out, int out_size, void* d_ws, size_t ws_size,
                              hipStream_t stream) {
    const float* x     = (const float*)d_in[0];  // [512,128]
    const float* w_in  = (const float*)d_in[1];  // [16,128]
    const float* b_in  = (const float*)d_in[2];  // [16]
    // d_in[3] = q_weights — unused: RZ phases cancel in Z-basis probabilities.
    const float* w_out = (const float*)d_in[4];  // [128,16]
    const float* b_out = (const float*)d_in[5];  // [128]
    float* out = (float*)d_out;                  // [512,128]

    const int B = in_sizes[0] / D;  // 512
    qlayer_kernel<<<B, D, 0, stream>>>(x, w_in, b_in, w_out, b_out, out);
}